// Round 5
// baseline (394.878 us; speedup 1.0000x reference)
//
#include <hip/hip_runtime.h>
#include <math.h>

#define BATCH  16
#define F_IN   16
#define F_OUT  64
#define NGRID  32
#define NSPEC  256
#define NU     136           // triangular (l,m>=0) count
#define NITEMS 496           // (m>=0, n) items
#define NP     2856          // packed (item,l) count = sum (l+1)(2l+1)
#define SCALING 0.005524271728019903f
#define PI_F 3.14159265358979323846f
#define W32 0.19634954084936207f   // 2*pi/32

// cof2[l] = c_off[l] + 2l(l+1): wig_so3 offset = cof2[l] + m*(2l+1) + n
__device__ const int d_cof2[16] = {0,5,22,59,124,225,370,567,824,1149,1550,2035,2612,3289,4074,4975};
// cumO[lam]: packed-p start of lam-group; item t in group has run O = cumO + (t-base)*(16-lam)
__device__ const int d_cumO[16] = {0,16,91,217,386,590,821,1071,1332,1596,1855,2101,2326,2522,2681,2795};

// decode packed p -> (l, m, n, lam)
__device__ __forceinline__ void decode_p(int p, int& l, int& m, int& n, int& lam) {
    int L = 0;
    #pragma unroll
    for (int q = 1; q < 16; ++q) if (p >= d_cumO[q]) L = q;
    const int len = 16 - L;
    int q = p - d_cumO[L];
    int ti = (int)((float)q * (1.0f / (float)len));
    int r = q - ti * len;
    if (r < 0) { ti--; r += len; }
    else if (r >= len) { ti++; r -= len; }
    l = L + r;
    lam = L;
    if (ti < 2 * L + 1) { m = L; n = ti - L; }
    else { const int r2 = ti - (2 * L + 1); m = r2 >> 1; n = (r2 & 1) ? L : -L; }
}

// ---------------- K_prep: merged k1 (blocks 0..255), k2 (256..511), k0 (512..690) ----------------
__global__ __launch_bounds__(256) void k_prep(const float* __restrict__ x,
                                              const float* __restrict__ wig_s2,
                                              const float* __restrict__ kern,
                                              const float* __restrict__ fk_re,
                                              const float* __restrict__ fk_im,
                                              const float* __restrict__ wig,
                                              float2* __restrict__ fhat,
                                              float2* __restrict__ psic,
                                              float2* __restrict__ wigt2) {
    __shared__ __align__(16) char smem[25088];
    const int blk = blockIdx.x;
    const int tid = threadIdx.x;

    if (blk < 256) {
        // ---- k1: fhat_t[b][u][f] ----
        float (*xs)[65]  = (float (*)[65])smem;            // 64*65*4 = 16640
        float2 (*xf)[65] = (float2 (*)[65])(smem + 16640); // 16*65*8 = 8320
        const int b = blk >> 4, f = blk & 15;

        const float4* src = (const float4*)(x + (size_t)(b * F_IN + f) * 4096);
        for (int t = tid; t < 1024; t += 256) {
            float4 v = src[t];
            const int row = t >> 4, col = (t & 15) * 4;
            xs[row][col] = v.x; xs[row][col+1] = v.y; xs[row][col+2] = v.z; xs[row][col+3] = v.w;
        }
        __syncthreads();
        {
            const int m = tid >> 4, j0 = tid & 15;
            float stc, sts;
            sincosf(-(2.f * PI_F / 64.f) * (float)m, &sts, &stc);
            float wr = 1.f, wi = 0.f;
            float ar[4] = {0,0,0,0}, ai[4] = {0,0,0,0};
            #pragma unroll 8
            for (int a = 0; a < 64; ++a) {
                #pragma unroll
                for (int q = 0; q < 4; ++q) {
                    const float v = xs[j0 + 16*q][a];
                    ar[q] += v * wr; ai[q] += v * wi;
                }
                const float nr = wr*stc - wi*sts; wi = wr*sts + wi*stc; wr = nr;
            }
            #pragma unroll
            for (int q = 0; q < 4; ++q) xf[m][j0 + 16*q] = make_float2(ar[q], ai[q]);
        }
        __syncthreads();
        if (tid < NU) {
            int l = (int)((sqrtf(8.f * (float)tid + 1.f) - 1.f) * 0.5f);
            while ((l + 1) * (l + 2) / 2 <= tid) ++l;
            while (l * (l + 1) / 2 > tid) --l;
            const int m = tid - l * (l + 1) / 2;
            const int s = l * l + l + m;
            float re = 0.f, im = 0.f;
            #pragma unroll 8
            for (int j = 0; j < 64; ++j) {
                const float2 v = xf[m][j];
                const float w = wig_s2[j * NSPEC + s];
                re += v.x * w; im += v.y * w;
            }
            fhat[(b * NU + tid) * F_IN + f] = make_float2(re, im);
        }
    } else if (blk < 512) {
        // ---- k2: psic_t[o][s][i] ----
        float2* fk = (float2*)smem;
        const int s = blk - 256;
        if (tid < NGRID) fk[tid] = make_float2(fk_re[s * NGRID + tid], -fk_im[s * NGRID + tid]);
        __syncthreads();
        for (int t = tid; t < F_OUT * F_IN; t += 256) {
            const int o = t >> 4, i = t & 15;
            const float4* kr = (const float4*)(kern + (size_t)(i * F_OUT + o) * NGRID);
            float re = 0.f, im = 0.f;
            #pragma unroll
            for (int g4 = 0; g4 < 8; ++g4) {
                const float4 v = kr[g4];
                const float2 a = fk[g4*4+0], b2 = fk[g4*4+1], c = fk[g4*4+2], d = fk[g4*4+3];
                re += v.x * a.x + v.y * b2.x + v.z * c.x + v.w * d.x;
                im += v.x * a.y + v.y * b2.y + v.z * c.y + v.w * d.y;
            }
            psic[(o * NSPEC + s) * F_IN + i] = make_float2(re * SCALING, im * SCALING);
        }
    } else {
        // ---- k0: wigt2[kp][p] = {wig[2kp][wo], wig[2kp+1][wo]} ----
        const int t = (blk - 512) * 256 + tid;
        if (t < NP * 16) {
            const int p = t >> 4, kp = t & 15;
            int l, m, n, lam;
            decode_p(p, l, m, n, lam);
            const int wo = d_cof2[l] + m * (2 * l + 1) + n;
            float2 v;
            v.x = wig[(2 * kp + 0) * 5456 + wo];
            v.y = wig[(2 * kp + 1) * 5456 + wo];
            wigt2[(size_t)kp * NP + p] = v;
        }
    }
}

// ---------------- K3a: fzp[bo][p] packed (item,l), from LDS-staged panels ----------------
__global__ __launch_bounds__(256) void k3a_fz(const float2* __restrict__ fhat,
                                              const float2* __restrict__ psic,
                                              float2* __restrict__ fzp) {
    __shared__ __align__(16) float2 fh[NU][18];
    __shared__ __align__(16) float2 ps[NSPEC][18];
    const int bo = blockIdx.x;
    const int b = bo >> 6, o = bo & 63;
    const int tid = threadIdx.x;

    {
        const float2* src = fhat + (size_t)b * NU * F_IN;
        for (int t = tid; t < NU * F_IN; t += 256) fh[t >> 4][t & 15] = src[t];
        const float2* src2 = psic + (size_t)o * NSPEC * F_IN;
        for (int t = tid; t < NSPEC * F_IN; t += 256) ps[t >> 4][t & 15] = src2[t];
    }
    __syncthreads();

    float2* dst = fzp + (size_t)bo * NP;
    for (int p = tid; p < NP; p += 256) {
        int l, m, n, lam;
        decode_p(p, l, m, n, lam);
        const int u = l * (l + 1) / 2 + m;
        const int sn = l * l + l + n;
        const float4* A4 = (const float4*)&fh[u][0];
        const float4* C4 = (const float4*)&ps[sn][0];
        float re = 0.f, im = 0.f;
        #pragma unroll
        for (int i2 = 0; i2 < 8; ++i2) {
            const float4 A = A4[i2], C = C4[i2];
            re += A.x*C.x - A.y*C.y + A.z*C.z - A.w*C.w;
            im += A.x*C.y + A.y*C.x + A.z*C.w + A.w*C.z;
        }
        dst[p] = make_float2(re, im);
    }
}

// ---------------- K3c: per (bo, 2 k's): S (streamed) -> G -> out; 17.2 KB LDS ----------------
__global__ __launch_bounds__(256) void k3c_main(const float2* __restrict__ fzp,
                                               const float2* __restrict__ wigt2,
                                               const float* __restrict__ bias,
                                               float* __restrict__ out) {
    __shared__ __align__(16) float2 S[2][16][33];   // 8448 B; reused as out staging
    __shared__ __align__(16) float2 G[2][16][33];   // 8448 B
    __shared__ float2 tw[32];                       // e^{+i q w}
    const int bo = blockIdx.x >> 4;
    const int kc = blockIdx.x & 15;                 // k-pair; k = 2*kc + kk
    const int tid = threadIdx.x;
    const float bb = bias[bo & 63];

    if (tid < 32) {
        float s_, c_;
        sincosf(W32 * (float)tid, &s_, &c_);
        tw[tid] = make_float2(c_, s_);
    }

    const float2* fzb = fzp + (size_t)bo * NP;
    const float2* wtb = wigt2 + (size_t)kc * NP;

    // ----- S-stage: 496 items sorted by lam; contiguous fz float2 + contiguous wigt float2 -----
    #pragma unroll
    for (int it = 0; it < 2; ++it) {
        const int t = tid + it * 256;
        if (t < NITEMS) {
            int lam = (int)sqrtf((float)t * 0.5f);
            while ((2*lam + 1) * (lam + 1) <= t) ++lam;
            while (lam > 0 && (2*lam - 1) * lam > t) --lam;
            const int r = t - (2*lam - 1) * lam;
            int m, n;
            if (r < 2*lam + 1) { m = lam; n = r - lam; }
            else { const int r2 = r - (2*lam + 1); m = r2 >> 1; n = (r2 & 1) ? lam : -lam; }
            const int len = 16 - lam;
            const int O = d_cumO[lam] + r * len;
            const float2* fz = fzb + O;
            const float2* wt = wtb + O;
            float sr0=0,si0=0,sr1=0,si1=0;
            for (int j = 0; j < len; ++j) {
                const float2 z = fz[j];
                const float2 w = wt[j];
                sr0 += z.x * w.x; si0 += z.y * w.x;
                sr1 += z.x * w.y; si1 += z.y * w.y;
            }
            const int nn = n + 15;
            S[0][m][nn] = make_float2(sr0, si0);
            S[1][m][nn] = make_float2(sr1, si1);
        }
    }
    __syncthreads();

    // ----- G-phase: G[kk][m][g] = sum_n S[kk][m][n] e^{i n g w} -----
    {
        const int kk = tid >> 7, m = (tid >> 3) & 15, g0 = tid & 7;
        float ar[2] = {0,0}, ai[2] = {0,0}, br[2] = {0,0}, bi[2] = {0,0};
        const float2* Srow = &S[kk][m][0];
        #pragma unroll
        for (int nn = 0; nn < 31; ++nn) {
            const float2 sv = Srow[nn];
            const int n = nn - 15;
            #pragma unroll
            for (int q = 0; q < 2; ++q) {
                const int g = g0 + 8 * q;
                const float2 w = tw[(n * g) & 31];
                const float X = sv.x * w.x - sv.y * w.y;
                const float Y = sv.x * w.y + sv.y * w.x;
                ar[q] += X; ai[q] += Y;
                if (nn & 1) { br[q] += X; bi[q] += Y; }   // n even
                else        { br[q] -= X; bi[q] -= Y; }   // n odd: e^{i n pi} = -1
            }
        }
        #pragma unroll
        for (int q = 0; q < 2; ++q) {
            const int g = g0 + 8 * q;
            G[kk][m][g]      = make_float2(ar[q], ai[q]);
            G[kk][m][g + 16] = make_float2(br[q], bi[q]);
        }
    }
    __syncthreads();

    // ----- out-phase: out[a,g] = ReG[0,g] + 2 sum_m Re(G[m,g] e^{i m a w}) + bias -----
    float* outs = (float*)&S[0][0][0];   // 2*32*32 floats = 8192 B
    {
        const int kk = tid >> 7, g = tid & 31, a0 = (tid >> 5) & 3;
        const float base = G[kk][0][g].x + bb;
        float o_[2][4];
        #pragma unroll
        for (int rep = 0; rep < 2; ++rep)
            #pragma unroll
            for (int j = 0; j < 4; ++j) o_[rep][j] = base;
        #pragma unroll
        for (int m = 1; m < 16; ++m) {
            const float2 gv = G[kk][m][g];
            const float gx = 2.f * gv.x, gy = 2.f * gv.y;
            #pragma unroll
            for (int rep = 0; rep < 2; ++rep) {
                const int A = a0 + 4 * rep;
                const float2 w = tw[(m * A) & 31];
                const float X = gx * w.x - gy * w.y;
                const float Y = gx * w.y + gy * w.x;
                o_[rep][0] += X;
                o_[rep][1] += ((m & 3) == 1) ? -Y : ((m & 3) == 2) ? -X : ((m & 3) == 3) ? Y : X;
                o_[rep][2] += (m & 1) ? -X : X;
                o_[rep][3] += ((m & 3) == 1) ? Y : ((m & 3) == 2) ? -X : ((m & 3) == 3) ? -Y : X;
            }
        }
        #pragma unroll
        for (int rep = 0; rep < 2; ++rep) {
            #pragma unroll
            for (int j = 0; j < 4; ++j) {
                const int a = a0 + 4*rep + 8*j;
                outs[kk * 1024 + (a << 5) + g] = o_[rep][j];
            }
        }
    }
    __syncthreads();

    {
        const int k0 = kc * 2;
        float4* dst = (float4*)(out + (((size_t)bo << 15) + ((size_t)k0 << 10)));
        const float4* s4 = (const float4*)outs;
        #pragma unroll
        for (int it = 0; it < 2; ++it) dst[tid + it * 256] = s4[tid + it * 256];
    }
}

extern "C" void kernel_launch(void* const* d_in, const int* in_sizes, int n_in,
                              void* d_out, int out_size, void* d_ws, size_t ws_size,
                              hipStream_t stream) {
    const float* x       = (const float*)d_in[0];
    const float* kern    = (const float*)d_in[1];
    const float* bias    = (const float*)d_in[2];
    const float* wig_s2  = (const float*)d_in[3];
    const float* fk_re   = (const float*)d_in[4];
    const float* fk_im   = (const float*)d_in[5];
    const float* wig_so3 = (const float*)d_in[6];
    float* out = (float*)d_out;

    // ws layout
    float2* fhat_t = (float2*)d_ws;                                   // 16*136*16*8   = 278528
    float2* psic_t = (float2*)((char*)d_ws + 327680);                 // 64*256*16*8   = 2097152
    float2* wigt2  = (float2*)((char*)d_ws + 2424832);                // 16*2856*8     = 365568
    float2* fzp    = (float2*)((char*)d_ws + 2790400);                // 1024*2856*8   = 23396352

    const int prep_blocks = 512 + (NP * 16 + 255) / 256;              // 512 + 179 = 691
    k_prep<<<prep_blocks, 256, 0, stream>>>(x, wig_s2, kern, fk_re, fk_im, wig_so3,
                                            fhat_t, psic_t, wigt2);
    k3a_fz<<<BATCH * F_OUT, 256, 0, stream>>>(fhat_t, psic_t, fzp);
    k3c_main<<<BATCH * F_OUT * 16, 256, 0, stream>>>(fzp, wigt2, bias, out);
}

// Round 6
// 296.687 us; speedup vs baseline: 1.3310x; 1.3310x over previous
//
#include <hip/hip_runtime.h>
#include <math.h>

#define BATCH  16
#define F_IN   16
#define F_OUT  64
#define NGRID  32
#define NSPEC  256
#define NU     136           // triangular (l,m>=0) count
#define NITEMS 496           // (m>=0, n) items
#define NP4    3680          // padded (item,l) count: runs padded to multiple of 4
#define SCALING 0.005524271728019903f
#define PI_F 3.14159265358979323846f
#define W32 0.19634954084936207f   // 2*pi/32

// cof2[l] = c_off[l] + 2l(l+1): wig_so3 offset = cof2[l] + m*(2l+1) + n
__device__ const int d_cof2[16] = {0,5,22,59,124,225,370,567,824,1149,1550,2035,2612,3289,4074,4975};
// PB[lam]: padded base of lam-group; run of item (lam,r) starts at PB[lam] + r*pl(lam), pl = (19-lam)&~3
__device__ const int d_PB[16] = {0,16,96,240,448,652,904,1204,1552,1816,2112,2440,2800,2996,3208,3436};

// decode item t (lam-sorted) -> lam, r, m, n
__device__ __forceinline__ void decode_item(int t, int& lam, int& r, int& m, int& n) {
    lam = (int)sqrtf((float)t * 0.5f);
    while ((2*lam + 1) * (lam + 1) <= t) ++lam;
    while (lam > 0 && (2*lam - 1) * lam > t) --lam;
    r = t - (2*lam - 1) * lam;
    if (r < 2*lam + 1) { m = lam; n = r - lam; }
    else { const int r2 = r - (2*lam + 1); m = r2 >> 1; n = (r2 & 1) ? lam : -lam; }
}

// decode padded index p4 -> l, m, n, valid
__device__ __forceinline__ void decode_p4(int p4, int& l, int& m, int& n, int& valid) {
    int lam = 0;
    #pragma unroll
    for (int q = 1; q < 16; ++q) if (p4 >= d_PB[q]) lam = q;
    const int pl = (19 - lam) & ~3;
    const int q2 = p4 - d_PB[lam];
    int ti = q2 / pl;
    const int j = q2 - ti * pl;
    l = lam + j;
    valid = (j < 16 - lam);
    if (l > 15) l = 15;
    if (ti < 2*lam + 1) { m = lam; n = ti - lam; }
    else { const int r2 = ti - (2*lam + 1); m = r2 >> 1; n = (r2 & 1) ? lam : -lam; }
}

// ---------------- K_prep: k1 (0..255) | k2 (256..511) | wigt4+p4lut (512..626) | itemlut (627..628) ----
__global__ __launch_bounds__(256) void k_prep(const float* __restrict__ x,
                                              const float* __restrict__ wig_s2,
                                              const float* __restrict__ kern,
                                              const float* __restrict__ fk_re,
                                              const float* __restrict__ fk_im,
                                              const float* __restrict__ wig,
                                              float2* __restrict__ fhat,
                                              float2* __restrict__ psic,
                                              float4* __restrict__ wigt4,
                                              unsigned int* __restrict__ p4lut,
                                              unsigned int* __restrict__ itemlut) {
    __shared__ __align__(16) char smem[25088];
    const int blk = blockIdx.x;
    const int tid = threadIdx.x;

    if (blk < 256) {
        // ---- k1: fhat_t[b][u][f] ----
        float (*xs)[65]  = (float (*)[65])smem;            // 64*65*4 = 16640
        float2 (*xf)[65] = (float2 (*)[65])(smem + 16640); // 16*65*8 = 8320
        const int b = blk >> 4, f = blk & 15;

        const float4* src = (const float4*)(x + (size_t)(b * F_IN + f) * 4096);
        for (int t = tid; t < 1024; t += 256) {
            float4 v = src[t];
            const int row = t >> 4, col = (t & 15) * 4;
            xs[row][col] = v.x; xs[row][col+1] = v.y; xs[row][col+2] = v.z; xs[row][col+3] = v.w;
        }
        __syncthreads();
        {
            const int m = tid >> 4, j0 = tid & 15;
            float stc, sts;
            sincosf(-(2.f * PI_F / 64.f) * (float)m, &sts, &stc);
            float wr = 1.f, wi = 0.f;
            float ar[4] = {0,0,0,0}, ai[4] = {0,0,0,0};
            #pragma unroll 8
            for (int a = 0; a < 64; ++a) {
                #pragma unroll
                for (int q = 0; q < 4; ++q) {
                    const float v = xs[j0 + 16*q][a];
                    ar[q] += v * wr; ai[q] += v * wi;
                }
                const float nr = wr*stc - wi*sts; wi = wr*sts + wi*stc; wr = nr;
            }
            #pragma unroll
            for (int q = 0; q < 4; ++q) xf[m][j0 + 16*q] = make_float2(ar[q], ai[q]);
        }
        __syncthreads();
        if (tid < NU) {
            int l = (int)((sqrtf(8.f * (float)tid + 1.f) - 1.f) * 0.5f);
            while ((l + 1) * (l + 2) / 2 <= tid) ++l;
            while (l * (l + 1) / 2 > tid) --l;
            const int m = tid - l * (l + 1) / 2;
            const int s = l * l + l + m;
            float re = 0.f, im = 0.f;
            #pragma unroll 8
            for (int j = 0; j < 64; ++j) {
                const float2 v = xf[m][j];
                const float w = wig_s2[j * NSPEC + s];
                re += v.x * w; im += v.y * w;
            }
            fhat[(b * NU + tid) * F_IN + f] = make_float2(re, im);
        }
    } else if (blk < 512) {
        // ---- k2: psic_t[o][s][i] ----
        float2* fk = (float2*)smem;
        const int s = blk - 256;
        if (tid < NGRID) fk[tid] = make_float2(fk_re[s * NGRID + tid], -fk_im[s * NGRID + tid]);
        __syncthreads();
        for (int t = tid; t < F_OUT * F_IN; t += 256) {
            const int o = t >> 4, i = t & 15;
            const float4* kr = (const float4*)(kern + (size_t)(i * F_OUT + o) * NGRID);
            float re = 0.f, im = 0.f;
            #pragma unroll
            for (int g4 = 0; g4 < 8; ++g4) {
                const float4 v = kr[g4];
                const float2 a = fk[g4*4+0], b2 = fk[g4*4+1], c = fk[g4*4+2], d = fk[g4*4+3];
                re += v.x * a.x + v.y * b2.x + v.z * c.x + v.w * d.x;
                im += v.x * a.y + v.y * b2.y + v.z * c.y + v.w * d.y;
            }
            psic[(o * NSPEC + s) * F_IN + i] = make_float2(re * SCALING, im * SCALING);
        }
    } else if (blk < 627) {
        // ---- wigt4[kc][p4] (+ p4lut when kc==0) ----
        const int t = (blk - 512) * 256 + tid;
        if (t < NP4 * 8) {
            const int p4 = t >> 3, kc = t & 7;
            int l, m, n, valid;
            decode_p4(p4, l, m, n, valid);
            const int wo = d_cof2[l] + m * (2 * l + 1) + n;
            float4 v = make_float4(0.f, 0.f, 0.f, 0.f);
            if (valid) {
                v.x = wig[(kc * 4 + 0) * 5456 + wo];
                v.y = wig[(kc * 4 + 1) * 5456 + wo];
                v.z = wig[(kc * 4 + 2) * 5456 + wo];
                v.w = wig[(kc * 4 + 3) * 5456 + wo];
            }
            wigt4[(size_t)kc * NP4 + p4] = v;
            if (kc == 0) {
                const int u  = l * (l + 1) / 2 + m;
                const int sn = l * l + l + n;
                p4lut[p4] = (unsigned)u | ((unsigned)sn << 8) | ((unsigned)valid << 16);
            }
        }
    } else {
        // ---- itemlut[t]: O4 | m<<12 | nn<<16 | nq<<21 ----
        const int t = (blk - 627) * 256 + tid;
        if (t < NITEMS) {
            int lam, r, m, n;
            decode_item(t, lam, r, m, n);
            const int pl = (19 - lam) & ~3;
            const int O4 = d_PB[lam] + r * pl;
            const int nq = pl >> 2;
            itemlut[t] = (unsigned)O4 | ((unsigned)m << 12) | ((unsigned)(n + 15) << 16) | ((unsigned)nq << 21);
        }
    }
}

// ---------------- K3a: fzp4[bo][p4] (padded, zeros in pad), from LDS-staged panels ----------------
__global__ __launch_bounds__(256) void k3a_fz(const float2* __restrict__ fhat,
                                              const float2* __restrict__ psic,
                                              const unsigned int* __restrict__ p4lut,
                                              float2* __restrict__ fzp) {
    __shared__ __align__(16) float2 fh[NU][18];
    __shared__ __align__(16) float2 ps[NSPEC][18];
    const int bo = blockIdx.x;
    const int b = bo >> 6, o = bo & 63;
    const int tid = threadIdx.x;

    {
        const float2* src = fhat + (size_t)b * NU * F_IN;
        for (int t = tid; t < NU * F_IN; t += 256) fh[t >> 4][t & 15] = src[t];
        const float2* src2 = psic + (size_t)o * NSPEC * F_IN;
        for (int t = tid; t < NSPEC * F_IN; t += 256) ps[t >> 4][t & 15] = src2[t];
    }
    __syncthreads();

    float2* dst = fzp + (size_t)bo * NP4;
    for (int p = tid; p < NP4; p += 256) {
        const unsigned e = p4lut[p];
        float2 outv = make_float2(0.f, 0.f);
        if (e >> 16) {
            const int u = e & 255, sn = (e >> 8) & 255;
            const float4* A4 = (const float4*)&fh[u][0];
            const float4* C4 = (const float4*)&ps[sn][0];
            float re = 0.f, im = 0.f;
            #pragma unroll
            for (int i2 = 0; i2 < 8; ++i2) {
                const float4 A = A4[i2], C = C4[i2];
                re += A.x*C.x - A.y*C.y + A.z*C.z - A.w*C.w;
                im += A.x*C.y + A.y*C.x + A.z*C.w + A.w*C.z;
            }
            outv = make_float2(re, im);
        }
        dst[p] = outv;
    }
}

// ---------------- K3c: per (bo, 4 k's): S (padded unroll-4 stream) -> G -> direct-store out ----
__global__ __launch_bounds__(256) void k3c_main(const float2* __restrict__ fzp,
                                               const float4* __restrict__ wigt4,
                                               const unsigned int* __restrict__ itemlut,
                                               const float* __restrict__ bias,
                                               float* __restrict__ out) {
    __shared__ __align__(16) float2 S[4][16][33];   // 16896 B
    __shared__ __align__(16) float2 G[4][16][33];   // 16896 B
    __shared__ float2 tw[32];                       // e^{+i q w}
    const int bo = blockIdx.x >> 3;
    const int kc = blockIdx.x & 7;
    const int tid = threadIdx.x;
    const float bb = bias[bo & 63];

    if (tid < 32) {
        float s_, c_;
        sincosf(W32 * (float)tid, &s_, &c_);
        tw[tid] = make_float2(c_, s_);
    }

    const float2* fzb = fzp + (size_t)bo * NP4;
    const float4* wtb = wigt4 + (size_t)kc * NP4;

    // ----- S-stage: 496 items; padded runs, unroll-4 inner -----
    #pragma unroll
    for (int it = 0; it < 2; ++it) {
        const int t = tid + it * 256;
        if (t < NITEMS) {
            const unsigned e = itemlut[t];
            const int O4 = e & 0xFFF, m = (e >> 12) & 15, nn = (e >> 16) & 31, nq = (e >> 21) & 7;
            const float2* fz = fzb + O4;
            const float4* wt = wtb + O4;
            float sr0=0,si0=0,sr1=0,si1=0,sr2=0,si2=0,sr3=0,si3=0;
            for (int c = 0; c < nq; ++c) {
                #pragma unroll
                for (int j = 0; j < 4; ++j) {
                    const float2 z = fz[j];
                    const float4 w = wt[j];
                    sr0 += z.x * w.x; si0 += z.y * w.x;
                    sr1 += z.x * w.y; si1 += z.y * w.y;
                    sr2 += z.x * w.z; si2 += z.y * w.z;
                    sr3 += z.x * w.w; si3 += z.y * w.w;
                }
                fz += 4; wt += 4;
            }
            S[0][m][nn] = make_float2(sr0, si0);
            S[1][m][nn] = make_float2(sr1, si1);
            S[2][m][nn] = make_float2(sr2, si2);
            S[3][m][nn] = make_float2(sr3, si3);
        }
    }
    __syncthreads();

    // ----- G-phase: G[kk][m][g] = sum_n S[kk][m][n] e^{i n g w} -----
    {
        const int kk = tid >> 6, m = (tid >> 2) & 15, g0 = tid & 3;
        float ar[4] = {0,0,0,0}, ai[4] = {0,0,0,0}, br[4] = {0,0,0,0}, bi[4] = {0,0,0,0};
        const float2* Srow = &S[kk][m][0];
        #pragma unroll
        for (int nn = 0; nn < 31; ++nn) {
            const float2 sv = Srow[nn];
            const int n = nn - 15;
            #pragma unroll
            for (int q = 0; q < 4; ++q) {
                const int g = g0 + 4 * q;
                const float2 w = tw[(n * g) & 31];
                const float X = sv.x * w.x - sv.y * w.y;
                const float Y = sv.x * w.y + sv.y * w.x;
                ar[q] += X; ai[q] += Y;
                if (nn & 1) { br[q] += X; bi[q] += Y; }   // n even
                else        { br[q] -= X; bi[q] -= Y; }   // n odd: e^{i n pi} = -1
            }
        }
        #pragma unroll
        for (int q = 0; q < 4; ++q) {
            const int g = g0 + 4 * q;
            G[kk][m][g]      = make_float2(ar[q], ai[q]);
            G[kk][m][g + 16] = make_float2(br[q], bi[q]);
        }
    }
    __syncthreads();

    // ----- out-phase: direct global stores -----
    {
        const int kk = tid >> 6, g = tid & 31, a0 = (tid >> 5) & 1;
        const float base = G[kk][0][g].x + bb;
        float o_[4][4];
        #pragma unroll
        for (int rep = 0; rep < 4; ++rep)
            #pragma unroll
            for (int j = 0; j < 4; ++j) o_[rep][j] = base;
        #pragma unroll
        for (int m = 1; m < 16; ++m) {
            const float2 gv = G[kk][m][g];
            const float gx = 2.f * gv.x, gy = 2.f * gv.y;
            #pragma unroll
            for (int rep = 0; rep < 4; ++rep) {
                const int A = a0 + 2 * rep;
                const float2 w = tw[(m * A) & 31];
                const float X = gx * w.x - gy * w.y;
                const float Y = gx * w.y + gy * w.x;
                o_[rep][0] += X;
                o_[rep][1] += ((m & 3) == 1) ? -Y : ((m & 3) == 2) ? -X : ((m & 3) == 3) ? Y : X;
                o_[rep][2] += (m & 1) ? -X : X;
                o_[rep][3] += ((m & 3) == 1) ? Y : ((m & 3) == 2) ? -X : ((m & 3) == 3) ? -Y : X;
            }
        }
        float* ob = out + (((size_t)bo << 15) + ((size_t)(kc * 4 + kk) << 10));
        #pragma unroll
        for (int rep = 0; rep < 4; ++rep) {
            #pragma unroll
            for (int j = 0; j < 4; ++j) {
                const int a = a0 + 2*rep + 8*j;
                ob[(a << 5) + g] = o_[rep][j];
            }
        }
    }
}

extern "C" void kernel_launch(void* const* d_in, const int* in_sizes, int n_in,
                              void* d_out, int out_size, void* d_ws, size_t ws_size,
                              hipStream_t stream) {
    const float* x       = (const float*)d_in[0];
    const float* kern    = (const float*)d_in[1];
    const float* bias    = (const float*)d_in[2];
    const float* wig_s2  = (const float*)d_in[3];
    const float* fk_re   = (const float*)d_in[4];
    const float* fk_im   = (const float*)d_in[5];
    const float* wig_so3 = (const float*)d_in[6];
    float* out = (float*)d_out;

    // ws layout
    float2*       fhat_t  = (float2*)d_ws;                              // 16*136*16*8 = 278528
    float2*       psic_t  = (float2*)((char*)d_ws + 327680);            // 64*256*16*8 = 2097152
    float4*       wigt4   = (float4*)((char*)d_ws + 2424832);           // 8*3680*16   = 470720
    unsigned int* p4lut   = (unsigned int*)((char*)d_ws + 2895872);     // 3680*4      = 14720
    unsigned int* itemlut = (unsigned int*)((char*)d_ws + 2910592);     // 496*4       = 1984
    float2*       fzp4    = (float2*)((char*)d_ws + 2912768);           // 1024*3680*8 = 30146560

    k_prep<<<629, 256, 0, stream>>>(x, wig_s2, kern, fk_re, fk_im, wig_so3,
                                    fhat_t, psic_t, wigt4, p4lut, itemlut);
    k3a_fz<<<BATCH * F_OUT, 256, 0, stream>>>(fhat_t, psic_t, p4lut, fzp4);
    k3c_main<<<BATCH * F_OUT * 8, 256, 0, stream>>>(fzp4, wigt4, itemlut, bias, out);
}